// Round 12
// baseline (1023.485 us; speedup 1.0000x reference)
//
#include <hip/hip_runtime.h>
#include <math.h>

#define NN 50000
#define MP 50048          // NN padded to multiple of 128 (32 rows x 4 waves)
#define NE 800000
#define FIN 64
#define HD 200
#define NG 256
#define SCAN_B 256
#define KPAD 224          // HD padded to multiple of 32 for MFMA K-steps
#define NT 13             // 13 * 16 = 208 >= 200 output col tiles
#define HB 12544          // LDS histogram packed dwords (covers 25088 nodes/pass)
#define PER_B 3125        // NE / 256 edges per histogram block

typedef _Float16 h16;
typedef __attribute__((ext_vector_type(8))) _Float16 half8;
typedef __attribute__((ext_vector_type(4))) float float4v;
typedef unsigned long long u64;

// ---------- dual histogram: blocks 0-255 src -> pSrc, 256-511 dst -> pDst ----------
__global__ __launch_bounds__(256) void k_hist(const int* __restrict__ src,
                                              const int* __restrict__ dst,
                                              unsigned* __restrict__ pSrc,
                                              unsigned* __restrict__ pDst, int E) {
    __shared__ unsigned h[HB];
    int tid = threadIdx.x;
    int isDst = blockIdx.x >> 8;
    int b = blockIdx.x & 255;
    const int* idx = isDst ? dst : src;
    unsigned* partial = isDst ? pDst : pSrc;
    int e0 = b * PER_B;
    int v[13];
#pragma unroll
    for (int j = 0; j < 13; ++j) {
        int o = j * 256 + tid;
        v[j] = (o < PER_B) ? idx[e0 + o] : -1;
    }
#pragma unroll
    for (int pass = 0; pass < 2; ++pass) {
        for (int t = tid; t < HB; t += 256) h[t] = 0;
        __syncthreads();
        int lo = pass * (2 * HB);
#pragma unroll
        for (int j = 0; j < 13; ++j) {
            int vv = v[j] - lo;
            if (vv >= 0 && vv < 2 * HB)
                atomicAdd(&h[vv >> 1], (vv & 1) ? 0x10000u : 1u);
        }
        __syncthreads();
        unsigned* pb = partial + ((size_t)pass * 256 + b) * HB;
        for (int t = tid; t < HB; t += 256) pb[t] = h[t];
        __syncthreads();
    }
}

// ---------- fused: reduce src partials -> degi ; scan dst partials -> bases + cntd ----------
__global__ void k_hredscan(const unsigned* __restrict__ pSrc, unsigned* __restrict__ pDst,
                           int* __restrict__ degi, int* __restrict__ cntd, int n) {
    int i = blockIdx.x * blockDim.x + threadIdx.x;
    if (i < 2 * HB) {
        int pass = i / HB, p = i - pass * HB;
        const unsigned* pb = pSrc + (size_t)pass * 256 * HB + p;
        unsigned s = 0;
        for (int b = 0; b < 256; ++b) s += pb[(size_t)b * HB];
        int n0 = pass * 2 * HB + 2 * p;
        if (n0 < n)     degi[n0]     = (int)(s & 0xffffu);
        if (n0 + 1 < n) degi[n0 + 1] = (int)(s >> 16);
    } else if (i < 4 * HB) {
        int j = i - 2 * HB;
        int pass = j / HB, p = j - pass * HB;
        unsigned* pb = pDst + (size_t)pass * 256 * HB + p;
        unsigned run = 0;
        for (int b = 0; b < 256; ++b) {
            unsigned c = pb[(size_t)b * HB];
            pb[(size_t)b * HB] = run;
            run += c;
        }
        int n0 = pass * 2 * HB + 2 * p;
        if (n0 < n)     cntd[n0]     = (int)(run & 0xffffu);
        if (n0 + 1 < n) cntd[n0 + 1] = (int)(run >> 16);
    }
}

// ---------- fused node prep (dis/qs/diag) + graph bounds ----------
__global__ void k_prep(const int* __restrict__ degi, const int* __restrict__ batch,
                       const float* __restrict__ lmax, float* __restrict__ dis,
                       float* __restrict__ qs, float* __restrict__ diag,
                       int* __restrict__ gstart, int n, int gN) {
    int b = blockIdx.x;
    if (b < gN) {
        int i = b * 256 + threadIdx.x;
        if (i < n) {
            int d = degi[i];
            float di = (d > 0) ? (1.0f / sqrtf((float)d)) : 0.0f;
            float sc = 2.0f / lmax[batch[i]];
            dis[i] = di;
            qs[i] = -di * sc;
            diag[i] = sc - 1.0f;
        }
    } else {
        int g = (b - gN) * 256 + threadIdx.x;
        if (g > NG) return;
        if (g == NG) { gstart[NG] = n; return; }
        int lo = 0, hi = n;
        while (lo < hi) {
            int mid = (lo + hi) >> 1;
            if (batch[mid] < g) lo = mid + 1; else hi = mid;
        }
        gstart[g] = lo;
    }
}

// ---------- exclusive scan over cnt_dst ----------
__global__ void k_scan1(const int* __restrict__ cnt, int* __restrict__ excl,
                        int* __restrict__ bsum, int n) {
    __shared__ int sh[SCAN_B];
    int tid = threadIdx.x;
    int i = blockIdx.x * SCAN_B + tid;
    int v = (i < n) ? cnt[i] : 0;
    sh[tid] = v;
    __syncthreads();
    for (int off = 1; off < SCAN_B; off <<= 1) {
        int t = (tid >= off) ? sh[tid - off] : 0;
        __syncthreads();
        sh[tid] += t;
        __syncthreads();
    }
    if (i < n) excl[i] = sh[tid] - v;
    if (tid == SCAN_B - 1) bsum[blockIdx.x] = sh[tid];
}

__global__ void k_scan2(int* __restrict__ bsum, int nb) {
    __shared__ int sh[SCAN_B];
    int tid = threadIdx.x;
    int v = (tid < nb) ? bsum[tid] : 0;
    sh[tid] = v;
    __syncthreads();
    for (int off = 1; off < SCAN_B; off <<= 1) {
        int t = (tid >= off) ? sh[tid - off] : 0;
        __syncthreads();
        sh[tid] += t;
        __syncthreads();
    }
    if (tid < nb) bsum[tid] = sh[tid] - v;   // exclusive
}

__global__ void k_scan3(int* __restrict__ excl, const int* __restrict__ bsum, int n) {
    int i = blockIdx.x * SCAN_B + threadIdx.x;
    if (i < n) excl[i] += bsum[blockIdx.x];
}

// ---------- CSR fill, zero global atomics (bases from scanned dst partials) ----------
__global__ __launch_bounds__(256) void k_fillcsr2(
    const int* __restrict__ src, const int* __restrict__ dst,
    const float* __restrict__ qs, const float* __restrict__ dis,
    const int* __restrict__ rowst, const unsigned* __restrict__ hpart,
    u64* __restrict__ csr, int E) {
    __shared__ unsigned lrank[HB];
    int tid = threadIdx.x;
    int e0 = blockIdx.x * PER_B;
    int vs[13], vd[13];
#pragma unroll
    for (int j = 0; j < 13; ++j) {
        int o = j * 256 + tid;
        vs[j] = (o < PER_B) ? src[e0 + o] : -1;
        vd[j] = (o < PER_B) ? dst[e0 + o] : -1;
    }
#pragma unroll
    for (int pass = 0; pass < 2; ++pass) {
        for (int t = tid; t < HB; t += 256) lrank[t] = 0;
        __syncthreads();
        int lo = pass * (2 * HB);
        const unsigned* base = hpart + ((size_t)pass * 256 + blockIdx.x) * HB;
#pragma unroll
        for (int j = 0; j < 13; ++j) {
            int vv = vd[j] - lo;
            if (vv >= 0 && vv < 2 * HB) {
                unsigned old = atomicAdd(&lrank[vv >> 1], (vv & 1) ? 0x10000u : 1u);
                unsigned rank = (vv & 1) ? (old >> 16) : (old & 0xffffu);
                unsigned bs = base[vv >> 1];
                unsigned bb = (vv & 1) ? (bs >> 16) : (bs & 0xffffu);
                int s = vs[j], d = vd[j];
                int pos = rowst[d] + (int)bb + (int)rank;
                float w = qs[s] * dis[d];
                csr[pos] = (unsigned)s | ((u64)__float_as_uint(w) << 32);
            }
        }
        __syncthreads();
    }
}

// ---------- fp32 -> fp16 split for x ----------
__global__ void k_split(const float* __restrict__ x, h16* __restrict__ x16, int total) {
    int i = blockIdx.x * blockDim.x + threadIdx.x;
    if (i < total) x16[i] = (h16)x[i];
}

// ---------- W pre-transpose, all 4 layers in one launch ----------
// fp16 [seg][ks][208][32]; B k-pads are ZERO -> A k-pads never need zeroing.
__global__ void k_wprep(const float* __restrict__ W1, const float* __restrict__ W2,
                        const float* __restrict__ W3, const float* __restrict__ W4,
                        h16* __restrict__ wt0, h16* __restrict__ wt1,
                        h16* __restrict__ wt2, h16* __restrict__ wt3) {
    const int T0 = 3 * 2 * 208 * 32, T = 3 * 7 * 208 * 32;
    int idx = blockIdx.x * blockDim.x + threadIdx.x;
    const float* W; h16* o; int fin, ksteps, li;
    if (idx < T0) { W = W1; o = wt0; fin = FIN; ksteps = 2; li = idx; }
    else {
        int r = idx - T0; int l = r / T;
        if (l > 2) return;
        li = r - l * T; fin = HD; ksteps = 7;
        W = (l == 0) ? W2 : ((l == 1) ? W3 : W4);
        o = (l == 0) ? wt1 : ((l == 1) ? wt2 : wt3);
    }
    int kk = li & 31;
    int r2 = li >> 5;
    int nn = r2 % 208;
    int r3 = r2 / 208;
    int ks = r3 % ksteps;
    int seg = r3 / ksteps;
    int k = ks * 32 + kk;
    o[li] = (nn < HD && k < fin) ? (h16)W[((size_t)seg * fin + k) * HD + nn] : (h16)0.f;
}

// ---------- standalone Tx1 gather (mode 0): one lane-group per node, 8-deep pipeline ----------
__global__ __launch_bounds__(256) void k_gather(
    const int* __restrict__ rowstart, const int* __restrict__ rowcnt,
    const u64* __restrict__ csr, const float* __restrict__ diag,
    const h16* __restrict__ hin16, h16* __restrict__ hout16,
    int s16, int lsh, int n) {
    int per = 256 >> lsh;
    int i = blockIdx.x * per + (threadIdx.x >> lsh);
    if (i >= n) return;
    int lane = threadIdx.x & ((1 << lsh) - 1);
    int c0 = lane * 4;
    if (c0 >= s16) return;
    int start = rowstart[i], cnt = rowcnt[i];
    float g0 = 0.f, g1 = 0.f, g2 = 0.f, g3 = 0.f;
    union U { uint2 u; h16 h[4]; };
    const u64* cp = csr + start;
    int k = 0;
    for (; k + 7 < cnt; k += 8) {
        u64 e[8];
#pragma unroll
        for (int j = 0; j < 8; ++j) e[j] = cp[k + j];
        U p[8];
#pragma unroll
        for (int j = 0; j < 8; ++j)
            p[j].u = *(const uint2*)(hin16 + (size_t)(unsigned)(e[j] & 0xffffffffu) * s16 + c0);
#pragma unroll
        for (int j = 0; j < 8; ++j) {
            float w = __uint_as_float((unsigned)(e[j] >> 32));
            g0 += w * (float)p[j].h[0];
            g1 += w * (float)p[j].h[1];
            g2 += w * (float)p[j].h[2];
            g3 += w * (float)p[j].h[3];
        }
    }
    for (; k < cnt; ++k) {
        u64 e0 = cp[k];
        U p0;
        p0.u = *(const uint2*)(hin16 + (size_t)(unsigned)(e0 & 0xffffffffu) * s16 + c0);
        float w = __uint_as_float((unsigned)(e0 >> 32));
        g0 += w * (float)p0.h[0];
        g1 += w * (float)p0.h[1];
        g2 += w * (float)p0.h[2];
        g3 += w * (float)p0.h[3];
    }
    float dg = diag[i];
    U hs; hs.u = *(const uint2*)(hin16 + (size_t)i * s16 + c0);
    U o;
    o.h[0] = (h16)(g0 + dg * (float)hs.h[0]);
    o.h[1] = (h16)(g1 + dg * (float)hs.h[1]);
    o.h[2] = (h16)(g2 + dg * (float)hs.h[2]);
    o.h[3] = (h16)(g3 + dg * (float)hs.h[3]);
    *(uint2*)(hout16 + (size_t)i * s16 + c0) = o.u;
}

// ---------- FUSED Tx2-gather + MFMA GEMM ----------
// Phase 1: each wave gathers Tx2 for ITS OWN 32 rows -> tx2 (global, L2-hot).
// Phase 2: barrier-free gemm out = relu([Tx0|Tx1|Tx2] @ W + b), A rows wave-local.
// No __syncthreads anywhere; __threadfence_block orders phase-1 stores vs phase-2 loads.
__global__ __launch_bounds__(256) void k_gg(
    const int* __restrict__ rowstart, const int* __restrict__ rowcnt,
    const u64* __restrict__ csr, const float* __restrict__ diag,
    const h16* hin, const h16* a0p, h16* tx2,        // hin=Tx1, a0p=Tx0 (may alias out16)
    int s16, int ksteps,
    const h16* __restrict__ Wt, const float* __restrict__ bias,
    h16* out16, int n) {
    int tid = threadIdx.x;
    int wave = tid >> 6, lane = tid & 63;
    int row0 = (blockIdx.x * 4 + wave) * 32;
    union U { uint2 u; h16 h[4]; };

    // ---- phase 1: gather Tx2 rows [row0, row0+32) ----
    int nsub   = (s16 == FIN) ? 4 : 1;                 // l0: 4 nodes in parallel (16-lane subgroups)
    int rounds = 32 / nsub;
    int sl     = (s16 == FIN) ? (lane >> 4) : 0;
    int cl     = (s16 == FIN) ? ((lane & 15) * 4) : (lane * 4);
    if (cl < s16) {
        for (int r = 0; r < rounds; ++r) {
            int i = row0 + r * nsub + sl;
            if (i >= n) continue;
            int start = rowstart[i], cnt = rowcnt[i];
            const u64* cp = csr + start;
            float g0 = 0.f, g1 = 0.f, g2 = 0.f, g3 = 0.f;
            int k = 0;
            for (; k + 7 < cnt; k += 8) {
                u64 e[8];
#pragma unroll
                for (int j = 0; j < 8; ++j) e[j] = cp[k + j];
                U p[8];
#pragma unroll
                for (int j = 0; j < 8; ++j)
                    p[j].u = *(const uint2*)(hin + (size_t)(unsigned)(e[j] & 0xffffffffu) * s16 + cl);
#pragma unroll
                for (int j = 0; j < 8; ++j) {
                    float w = __uint_as_float((unsigned)(e[j] >> 32));
                    g0 += w * (float)p[j].h[0];
                    g1 += w * (float)p[j].h[1];
                    g2 += w * (float)p[j].h[2];
                    g3 += w * (float)p[j].h[3];
                }
            }
            for (; k < cnt; ++k) {
                u64 e0 = cp[k];
                U p0;
                p0.u = *(const uint2*)(hin + (size_t)(unsigned)(e0 & 0xffffffffu) * s16 + cl);
                float w = __uint_as_float((unsigned)(e0 >> 32));
                g0 += w * (float)p0.h[0];
                g1 += w * (float)p0.h[1];
                g2 += w * (float)p0.h[2];
                g3 += w * (float)p0.h[3];
            }
            float dg = diag[i];
            U hs; hs.u = *(const uint2*)(hin + (size_t)i * s16 + cl);
            U h0; h0.u = *(const uint2*)(a0p + (size_t)i * s16 + cl);
            U o;
            o.h[0] = (h16)(2.f * (g0 + dg * (float)hs.h[0]) - (float)h0.h[0]);
            o.h[1] = (h16)(2.f * (g1 + dg * (float)hs.h[1]) - (float)h0.h[1]);
            o.h[2] = (h16)(2.f * (g2 + dg * (float)hs.h[2]) - (float)h0.h[2]);
            o.h[3] = (h16)(2.f * (g3 + dg * (float)hs.h[3]) - (float)h0.h[3]);
            *(uint2*)(tx2 + (size_t)i * s16 + cl) = o.u;
        }
    }
    __threadfence_block();   // drain phase-1 stores before phase-2 same-address loads

    // ---- phase 2: gemm (wave-local A rows) ----
    int nq = lane & 15, quad = lane >> 4;
    const h16* Aseg[3] = {a0p, hin, tx2};
    float4v acc[2][NT];
#pragma unroll
    for (int r = 0; r < 2; r++)
#pragma unroll
        for (int t = 0; t < NT; t++) acc[r][t] = (float4v)0.f;

    for (int seg = 0; seg < 3; ++seg) {
        const h16* Ab = Aseg[seg] + (size_t)(row0 + nq) * s16 + quad * 8;
        const h16* Bb = Wt + (size_t)seg * ksteps * 208 * 32 + (size_t)nq * 32 + quad * 8;
        for (int ks = 0; ks < ksteps; ++ks) {
            half8 af0 = *(const half8*)(Ab + ks * 32);
            half8 af1 = *(const half8*)(Ab + 16 * s16 + ks * 32);
            const h16* Bk = Bb + (size_t)ks * 208 * 32;
#pragma unroll
            for (int t = 0; t < NT; ++t) {
                half8 bf = *(const half8*)(Bk + t * 16 * 32);
                acc[0][t] = __builtin_amdgcn_mfma_f32_16x16x32_f16(af0, bf, acc[0][t], 0, 0, 0);
                acc[1][t] = __builtin_amdgcn_mfma_f32_16x16x32_f16(af1, bf, acc[1][t], 0, 0, 0);
            }
        }
    }
#pragma unroll
    for (int r = 0; r < 2; ++r) {
        int rowb = row0 + r * 16 + quad * 4;
#pragma unroll
        for (int t = 0; t < NT; ++t) {
            int col = t * 16 + nq;
            if (col >= HD) continue;
            float bj = bias[col];
#pragma unroll
            for (int g = 0; g < 4; ++g) {
                int row = rowb + g;
                if (row < n)
                    out16[(size_t)row * KPAD + col] = (h16)fmaxf(acc[r][t][g] + bj, 0.0f);
            }
        }
    }
}

// ---------- fused segmented pool (mean+max) + FC + log_softmax (fp16 input) ----------
__global__ __launch_bounds__(256) void k_pool_fc(
    const h16* __restrict__ Hf, const int* __restrict__ gstart,
    const float* __restrict__ fcw, const float* __restrict__ fcb,
    float* __restrict__ out) {
    __shared__ float red[8];
    int g = blockIdx.x;
    int j = threadIdx.x;
    int i0 = gstart[g], i1 = gstart[g + 1];
    float s0 = 0.f, s1 = 0.f, s2 = 0.f, s3 = 0.f, mx = 0.f;   // post-ReLU: max >= 0
    if (j < HD) {
        int i = i0;
        for (; i + 3 < i1; i += 4) {
            float v0 = (float)Hf[(size_t)i * KPAD + j];
            float v1 = (float)Hf[(size_t)(i + 1) * KPAD + j];
            float v2 = (float)Hf[(size_t)(i + 2) * KPAD + j];
            float v3 = (float)Hf[(size_t)(i + 3) * KPAD + j];
            s0 += v0; s1 += v1; s2 += v2; s3 += v3;
            mx = fmaxf(mx, fmaxf(fmaxf(v0, v1), fmaxf(v2, v3)));
        }
        for (; i < i1; ++i) {
            float v = (float)Hf[(size_t)i * KPAD + j];
            s0 += v; mx = fmaxf(mx, v);
        }
    }
    float cntf = (float)(i1 - i0);
    float mean = (s0 + s1 + s2 + s3) / fmaxf(cntf, 1.f);
    float p0 = 0.f, p1 = 0.f;
    if (j < HD) {
        p0 = mean * fcw[2 * j]     + mx * fcw[2 * (HD + j)];
        p1 = mean * fcw[2 * j + 1] + mx * fcw[2 * (HD + j) + 1];
    }
#pragma unroll
    for (int o = 32; o > 0; o >>= 1) {
        p0 += __shfl_down(p0, o);
        p1 += __shfl_down(p1, o);
    }
    int wave = j >> 6, lane = j & 63;
    if (lane == 0) { red[wave * 2] = p0; red[wave * 2 + 1] = p1; }
    __syncthreads();
    if (j == 0) {
        float z0 = red[0] + red[2] + red[4] + red[6] + fcb[0];
        float z1 = red[1] + red[3] + red[5] + red[7] + fcb[1];
        float m = fmaxf(z0, z1);
        float lse = m + logf(expf(z0 - m) + expf(z1 - m));
        out[g * 2 + 0] = z0 - lse;
        out[g * 2 + 1] = z1 - lse;
    }
}

extern "C" void kernel_launch(void* const* d_in, const int* in_sizes, int n_in,
                              void* d_out, int out_size, void* d_ws, size_t ws_size,
                              hipStream_t stream) {
    const float* x     = (const float*)d_in[0];
    const int*   edge  = (const int*)d_in[1];
    const int*   batch = (const int*)d_in[2];
    const float* lmax  = (const float*)d_in[3];
    const float* W1 = (const float*)d_in[4];  const float* b1 = (const float*)d_in[5];
    const float* W2 = (const float*)d_in[6];  const float* b2 = (const float*)d_in[7];
    const float* W3 = (const float*)d_in[8];  const float* b3 = (const float*)d_in[9];
    const float* W4 = (const float*)d_in[10]; const float* b4 = (const float*)d_in[11];
    const float* fcw = (const float*)d_in[12]; const float* fcb = (const float*)d_in[13];
    float* out = (float*)d_out;

    const int n = NN, E = NE;
    const int* src = edge;
    const int* dst = edge + E;

    // workspace layout (float units, each buffer 16B-aligned)
    float* ws = (float*)d_ws;
    size_t off = 0;
    auto alloc = [&](size_t nfloats) { float* p = ws + off; off += (nfloats + 3) & ~(size_t)3; return p; };
    int*   degi   = (int*)alloc(NN);
    float* dis    = alloc(NN);
    float* qs     = alloc(NN);
    float* diag   = alloc(NN);
    int*   cntd   = (int*)alloc(NN);
    int*   rowst  = (int*)alloc(NN);
    int*   bsum   = (int*)alloc(SCAN_B);
    u64*   csr    = (u64*)alloc((size_t)NE * 2);            // packed {src, w}
    int*   gstart = (int*)alloc(NG + 1);
    unsigned* pSrc = (unsigned*)alloc((size_t)2 * 256 * HB);  // src histogram partials
    unsigned* pDst = (unsigned*)alloc((size_t)2 * 256 * HB);  // dst histogram partials/bases
    h16*   x16    = (h16*)alloc((size_t)MP * FIN / 2);      // fp16 x (stride 64)
    h16*   hi0    = (h16*)alloc((size_t)MP * KPAD / 2);     // fp16 h (inter-layer, in-place)
    h16*   hi1    = (h16*)alloc((size_t)MP * KPAD / 2);     // fp16 Tx1
    h16*   hi2    = (h16*)alloc((size_t)MP * KPAD / 2);     // fp16 Tx2 scratch (fused)
    h16*   hi3    = (h16*)alloc((size_t)MP * KPAD / 2);     // fp16 final features (pool input)
    const int WSZ0 = 3 * 2 * 208 * 32;
    const int WSZ  = 3 * 7 * 208 * 32;
    h16* wt0 = (h16*)alloc(WSZ0 / 2);
    h16* wt1 = (h16*)alloc(WSZ / 2);
    h16* wt2 = (h16*)alloc(WSZ / 2);
    h16* wt3 = (h16*)alloc(WSZ / 2);

    dim3 blk(256);
    int gN = (n + 255) / 256;
    int gScan = (n + SCAN_B - 1) / SCAN_B;
    int gGemm = MP / 128;                       // 391 blocks, 4 waves x 32 rows
    int gWp = (WSZ0 + 3 * WSZ + 255) / 256;

    // --- setup (no memsets needed: every consumed byte is written this call;
    //     A k-pad/tail-row garbage is nullified by zeroed B k-pads + row<n store guard) ---
    k_wprep<<<gWp, blk, 0, stream>>>(W1, W2, W3, W4, wt0, wt1, wt2, wt3);
    k_split<<<(NN * FIN + 255) / 256, blk, 0, stream>>>(x, x16, NN * FIN);
    k_hist<<<512, blk, 0, stream>>>(src, dst, pSrc, pDst, E);
    k_hredscan<<<(4 * HB + 255) / 256, blk, 0, stream>>>(pSrc, pDst, degi, cntd, n);
    k_prep<<<gN + 2, blk, 0, stream>>>(degi, batch, lmax, dis, qs, diag, gstart, n, gN);
    k_scan1<<<gScan, blk, 0, stream>>>(cntd, rowst, bsum, n);
    k_scan2<<<1, blk, 0, stream>>>(bsum, gScan);
    k_scan3<<<gScan, blk, 0, stream>>>(rowst, bsum, n);
    k_fillcsr2<<<256, blk, 0, stream>>>(src, dst, qs, dis, rowst, pDst, csr, E);

    // --- 4 Chebyshev layers: standalone Tx1 gather + fused Tx2-gather/GEMM ---
    const h16* wt[4] = {wt0, wt1, wt2, wt3};
    const float* bl[4] = {b1, b2, b3, b4};
    for (int l = 0; l < 4; l++) {
        int s16 = (l == 0) ? FIN : KPAD;
        int lsh = (l == 0) ? 4 : 6;
        int per = 256 >> lsh;
        int gGat = (n + per - 1) / per;
        int ksteps = (l == 0) ? 2 : 7;
        const h16* a0 = (l == 0) ? x16 : hi0;
        // Tx1 = prop(Tx0) -> hi1
        k_gather<<<gGat, blk, 0, stream>>>(rowst, cntd, csr, diag, a0, hi1, s16, lsh, n);
        // fused: Tx2 rows (hi2) + out = relu([Tx0|Tx1|Tx2]@W + b)
        k_gg<<<gGemm, blk, 0, stream>>>(rowst, cntd, csr, diag, hi1, a0, hi2,
                                        s16, ksteps, wt[l], bl[l],
                                        (l < 3) ? hi0 : hi3, n);
    }

    // --- fused pool + FC head (no atomics; batch is sorted; fp16 input) ---
    k_pool_fc<<<NG, blk, 0, stream>>>(hi3, gstart, fcw, fcb, out);
}

// Round 13
// 802.077 us; speedup vs baseline: 1.2760x; 1.2760x over previous
//
#include <hip/hip_runtime.h>
#include <math.h>

#define NN 50000
#define MP 50048          // NN padded to multiple of 128 (32 rows x 4 waves)
#define NE 800000
#define FIN 64
#define HD 200
#define NG 256
#define SCAN_B 256
#define KPAD 224          // HD padded to multiple of 32 for MFMA K-steps
#define NT 13             // 13 * 16 = 208 >= 200 output col tiles
#define HB 12544          // LDS histogram packed dwords (covers 25088 nodes/pass)
#define PER_B 3125        // NE / 256 edges per histogram block

typedef _Float16 h16;
typedef __attribute__((ext_vector_type(8))) _Float16 half8;
typedef __attribute__((ext_vector_type(4))) float float4v;
typedef unsigned long long u64;

// ---------- dual histogram: blocks 0-255 src -> pSrc, 256-511 dst -> pDst ----------
__global__ __launch_bounds__(256) void k_hist(const int* __restrict__ src,
                                              const int* __restrict__ dst,
                                              unsigned* __restrict__ pSrc,
                                              unsigned* __restrict__ pDst, int E) {
    __shared__ unsigned h[HB];
    int tid = threadIdx.x;
    int isDst = blockIdx.x >> 8;
    int b = blockIdx.x & 255;
    const int* idx = isDst ? dst : src;
    unsigned* partial = isDst ? pDst : pSrc;
    int e0 = b * PER_B;
    int v[13];
#pragma unroll
    for (int j = 0; j < 13; ++j) {
        int o = j * 256 + tid;
        v[j] = (o < PER_B) ? idx[e0 + o] : -1;
    }
#pragma unroll
    for (int pass = 0; pass < 2; ++pass) {
        for (int t = tid; t < HB; t += 256) h[t] = 0;
        __syncthreads();
        int lo = pass * (2 * HB);
#pragma unroll
        for (int j = 0; j < 13; ++j) {
            int vv = v[j] - lo;
            if (vv >= 0 && vv < 2 * HB)
                atomicAdd(&h[vv >> 1], (vv & 1) ? 0x10000u : 1u);
        }
        __syncthreads();
        unsigned* pb = partial + ((size_t)pass * 256 + b) * HB;
        for (int t = tid; t < HB; t += 256) pb[t] = h[t];
        __syncthreads();
    }
}

// ---------- fused: reduce src partials -> degi ; scan dst partials -> bases + cntd ----------
__global__ void k_hredscan(const unsigned* __restrict__ pSrc, unsigned* __restrict__ pDst,
                           int* __restrict__ degi, int* __restrict__ cntd, int n) {
    int i = blockIdx.x * blockDim.x + threadIdx.x;
    if (i < 2 * HB) {
        int pass = i / HB, p = i - pass * HB;
        const unsigned* pb = pSrc + (size_t)pass * 256 * HB + p;
        unsigned s = 0;
        for (int b = 0; b < 256; ++b) s += pb[(size_t)b * HB];
        int n0 = pass * 2 * HB + 2 * p;
        if (n0 < n)     degi[n0]     = (int)(s & 0xffffu);
        if (n0 + 1 < n) degi[n0 + 1] = (int)(s >> 16);
    } else if (i < 4 * HB) {
        int j = i - 2 * HB;
        int pass = j / HB, p = j - pass * HB;
        unsigned* pb = pDst + (size_t)pass * 256 * HB + p;
        unsigned run = 0;
        for (int b = 0; b < 256; ++b) {
            unsigned c = pb[(size_t)b * HB];
            pb[(size_t)b * HB] = run;
            run += c;
        }
        int n0 = pass * 2 * HB + 2 * p;
        if (n0 < n)     cntd[n0]     = (int)(run & 0xffffu);
        if (n0 + 1 < n) cntd[n0 + 1] = (int)(run >> 16);
    }
}

// ---------- fused node prep (dis/qs/diag) + graph bounds ----------
__global__ void k_prep(const int* __restrict__ degi, const int* __restrict__ batch,
                       const float* __restrict__ lmax, float* __restrict__ dis,
                       float* __restrict__ qs, float* __restrict__ diag,
                       int* __restrict__ gstart, int n, int gN) {
    int b = blockIdx.x;
    if (b < gN) {
        int i = b * 256 + threadIdx.x;
        if (i < n) {
            int d = degi[i];
            float di = (d > 0) ? (1.0f / sqrtf((float)d)) : 0.0f;
            float sc = 2.0f / lmax[batch[i]];
            dis[i] = di;
            qs[i] = -di * sc;
            diag[i] = sc - 1.0f;
        }
    } else {
        int g = (b - gN) * 256 + threadIdx.x;
        if (g > NG) return;
        if (g == NG) { gstart[NG] = n; return; }
        int lo = 0, hi = n;
        while (lo < hi) {
            int mid = (lo + hi) >> 1;
            if (batch[mid] < g) lo = mid + 1; else hi = mid;
        }
        gstart[g] = lo;
    }
}

// ---------- exclusive scan over cnt_dst ----------
__global__ void k_scan1(const int* __restrict__ cnt, int* __restrict__ excl,
                        int* __restrict__ bsum, int n) {
    __shared__ int sh[SCAN_B];
    int tid = threadIdx.x;
    int i = blockIdx.x * SCAN_B + tid;
    int v = (i < n) ? cnt[i] : 0;
    sh[tid] = v;
    __syncthreads();
    for (int off = 1; off < SCAN_B; off <<= 1) {
        int t = (tid >= off) ? sh[tid - off] : 0;
        __syncthreads();
        sh[tid] += t;
        __syncthreads();
    }
    if (i < n) excl[i] = sh[tid] - v;
    if (tid == SCAN_B - 1) bsum[blockIdx.x] = sh[tid];
}

__global__ void k_scan2(int* __restrict__ bsum, int nb) {
    __shared__ int sh[SCAN_B];
    int tid = threadIdx.x;
    int v = (tid < nb) ? bsum[tid] : 0;
    sh[tid] = v;
    __syncthreads();
    for (int off = 1; off < SCAN_B; off <<= 1) {
        int t = (tid >= off) ? sh[tid - off] : 0;
        __syncthreads();
        sh[tid] += t;
        __syncthreads();
    }
    if (tid < nb) bsum[tid] = sh[tid] - v;   // exclusive
}

__global__ void k_scan3(int* __restrict__ excl, const int* __restrict__ bsum, int n) {
    int i = blockIdx.x * SCAN_B + threadIdx.x;
    if (i < n) excl[i] += bsum[blockIdx.x];
}

// ---------- CSR fill, zero global atomics (bases from scanned dst partials) ----------
__global__ __launch_bounds__(256) void k_fillcsr2(
    const int* __restrict__ src, const int* __restrict__ dst,
    const float* __restrict__ qs, const float* __restrict__ dis,
    const int* __restrict__ rowst, const unsigned* __restrict__ hpart,
    u64* __restrict__ csr, int E) {
    __shared__ unsigned lrank[HB];
    int tid = threadIdx.x;
    int e0 = blockIdx.x * PER_B;
    int vs[13], vd[13];
#pragma unroll
    for (int j = 0; j < 13; ++j) {
        int o = j * 256 + tid;
        vs[j] = (o < PER_B) ? src[e0 + o] : -1;
        vd[j] = (o < PER_B) ? dst[e0 + o] : -1;
    }
#pragma unroll
    for (int pass = 0; pass < 2; ++pass) {
        for (int t = tid; t < HB; t += 256) lrank[t] = 0;
        __syncthreads();
        int lo = pass * (2 * HB);
        const unsigned* base = hpart + ((size_t)pass * 256 + blockIdx.x) * HB;
#pragma unroll
        for (int j = 0; j < 13; ++j) {
            int vv = vd[j] - lo;
            if (vv >= 0 && vv < 2 * HB) {
                unsigned old = atomicAdd(&lrank[vv >> 1], (vv & 1) ? 0x10000u : 1u);
                unsigned rank = (vv & 1) ? (old >> 16) : (old & 0xffffu);
                unsigned bs = base[vv >> 1];
                unsigned bb = (vv & 1) ? (bs >> 16) : (bs & 0xffffu);
                int s = vs[j], d = vd[j];
                int pos = rowst[d] + (int)bb + (int)rank;
                float w = qs[s] * dis[d];
                csr[pos] = (unsigned)s | ((u64)__float_as_uint(w) << 32);
            }
        }
        __syncthreads();
    }
}

// ---------- W pre-transpose (all 4 layers) + x fp32->fp16, one launch ----------
// fp16 [seg][ks][208][32]; B k-pads are ZERO -> A k-pads never need zeroing.
__global__ void k_wprep(const float* __restrict__ W1, const float* __restrict__ W2,
                        const float* __restrict__ W3, const float* __restrict__ W4,
                        h16* __restrict__ wt0, h16* __restrict__ wt1,
                        h16* __restrict__ wt2, h16* __restrict__ wt3,
                        const float* __restrict__ x, h16* __restrict__ x16) {
    const int T0 = 3 * 2 * 208 * 32, T = 3 * 7 * 208 * 32;
    const int TW = T0 + 3 * T;
    int idx = blockIdx.x * blockDim.x + threadIdx.x;
    if (idx >= TW) {                      // tail: x split (NN*FIN elements)
        int i = idx - TW;
        if (i < NN * FIN) x16[i] = (h16)x[i];
        return;
    }
    const float* W; h16* o; int fin, ksteps, li;
    if (idx < T0) { W = W1; o = wt0; fin = FIN; ksteps = 2; li = idx; }
    else {
        int r = idx - T0; int l = r / T;
        li = r - l * T; fin = HD; ksteps = 7;
        W = (l == 0) ? W2 : ((l == 1) ? W3 : W4);
        o = (l == 0) ? wt1 : ((l == 1) ? wt2 : wt3);
    }
    int kk = li & 31;
    int r2 = li >> 5;
    int nn = r2 % 208;
    int r3 = r2 / 208;
    int ks = r3 % ksteps;
    int seg = r3 / ksteps;
    int k = ks * 32 + kk;
    o[li] = (nn < HD && k < fin) ? (h16)W[((size_t)seg * fin + k) * HD + nn] : (h16)0.f;
}

// ---------- propagation (gather, fp16, 12-deep load pipeline) ----------
// One lane-group per node: group = 2^lsh lanes (64 for s16=224, 16 for s16=64).
// Oversubscribed wave-per-node grid = the MLP that makes this fast (R12 lesson).
// mode 0: v = gath + diag*hin        mode 1: v = 2*(gath + diag*hin) - hin0
__global__ __launch_bounds__(256) void k_gather(
    const int* __restrict__ rowstart, const int* __restrict__ rowcnt,
    const u64* __restrict__ csr, const float* __restrict__ diag,
    const h16* __restrict__ hin16, const h16* __restrict__ h016,
    h16* __restrict__ hout16, int s16, int lsh, int n, int mode) {
    int per = 256 >> lsh;
    int i = blockIdx.x * per + (threadIdx.x >> lsh);
    if (i >= n) return;
    int lane = threadIdx.x & ((1 << lsh) - 1);
    int c0 = lane * 4;
    if (c0 >= s16) return;
    int start = rowstart[i], cnt = rowcnt[i];
    float g0 = 0.f, g1 = 0.f, g2 = 0.f, g3 = 0.f;
    union U { uint2 u; h16 h[4]; };
    const u64* cp = csr + start;
    int k = 0;
    for (; k + 11 < cnt; k += 12) {
        u64 e[12];
#pragma unroll
        for (int j = 0; j < 12; ++j) e[j] = cp[k + j];          // broadcast, independent
        U p[12];
#pragma unroll
        for (int j = 0; j < 12; ++j)                             // 12 rows in flight
            p[j].u = *(const uint2*)(hin16 + (size_t)(unsigned)(e[j] & 0xffffffffu) * s16 + c0);
#pragma unroll
        for (int j = 0; j < 12; ++j) {
            float w = __uint_as_float((unsigned)(e[j] >> 32));
            g0 += w * (float)p[j].h[0];
            g1 += w * (float)p[j].h[1];
            g2 += w * (float)p[j].h[2];
            g3 += w * (float)p[j].h[3];
        }
    }
    for (; k + 3 < cnt; k += 4) {
        u64 e[4];
#pragma unroll
        for (int j = 0; j < 4; ++j) e[j] = cp[k + j];
        U p[4];
#pragma unroll
        for (int j = 0; j < 4; ++j)
            p[j].u = *(const uint2*)(hin16 + (size_t)(unsigned)(e[j] & 0xffffffffu) * s16 + c0);
#pragma unroll
        for (int j = 0; j < 4; ++j) {
            float w = __uint_as_float((unsigned)(e[j] >> 32));
            g0 += w * (float)p[j].h[0];
            g1 += w * (float)p[j].h[1];
            g2 += w * (float)p[j].h[2];
            g3 += w * (float)p[j].h[3];
        }
    }
    for (; k < cnt; ++k) {
        u64 e0 = cp[k];
        U p0;
        p0.u = *(const uint2*)(hin16 + (size_t)(unsigned)(e0 & 0xffffffffu) * s16 + c0);
        float w = __uint_as_float((unsigned)(e0 >> 32));
        g0 += w * (float)p0.h[0];
        g1 += w * (float)p0.h[1];
        g2 += w * (float)p0.h[2];
        g3 += w * (float)p0.h[3];
    }
    float dg = diag[i];
    U hs; hs.u = *(const uint2*)(hin16 + (size_t)i * s16 + c0);
    float v0 = g0 + dg * (float)hs.h[0];
    float v1 = g1 + dg * (float)hs.h[1];
    float v2 = g2 + dg * (float)hs.h[2];
    float v3 = g3 + dg * (float)hs.h[3];
    if (mode == 1) {
        U h0; h0.u = *(const uint2*)(h016 + (size_t)i * s16 + c0);
        v0 = 2.f * v0 - (float)h0.h[0];
        v1 = 2.f * v1 - (float)h0.h[1];
        v2 = 2.f * v2 - (float)h0.h[2];
        v3 = 2.f * v3 - (float)h0.h[3];
    }
    U o;
    o.h[0] = (h16)v0; o.h[1] = (h16)v1; o.h[2] = (h16)v2; o.h[3] = (h16)v3;
    *(uint2*)(hout16 + (size_t)i * s16 + c0) = o.u;
}

// ---------- MFMA fp16 GEMM, barrier-free: out = relu([A0|A1|A2] @ W + b) ----------
// Each wave: 32 rows x 208 cols. In-place out16 over an A-buffer is safe:
// each row is read only by the wave that writes it, reads precede epilogue.
__global__ __launch_bounds__(256) void k_gemm16(
    const h16* __restrict__ A0, const h16* __restrict__ A1, const h16* __restrict__ A2,
    int strideA, int ksteps,
    const h16* __restrict__ Wt, const float* __restrict__ bias,
    h16* __restrict__ out16, int n) {
    int tid = threadIdx.x;
    int wave = tid >> 6, lane = tid & 63;
    int nq = lane & 15, quad = lane >> 4;
    int row0 = (blockIdx.x * 4 + wave) * 32;
    const h16* Aseg[3] = {A0, A1, A2};

    float4v acc[2][NT];
#pragma unroll
    for (int r = 0; r < 2; r++)
#pragma unroll
        for (int t = 0; t < NT; t++) acc[r][t] = (float4v)0.f;

    for (int seg = 0; seg < 3; ++seg) {
        const h16* Ab = Aseg[seg] + (size_t)(row0 + nq) * strideA + quad * 8;
        const h16* Bb = Wt + (size_t)seg * ksteps * 208 * 32 + (size_t)nq * 32 + quad * 8;
        for (int ks = 0; ks < ksteps; ++ks) {
            half8 af0 = *(const half8*)(Ab + ks * 32);
            half8 af1 = *(const half8*)(Ab + 16 * strideA + ks * 32);
            const h16* Bk = Bb + (size_t)ks * 208 * 32;
#pragma unroll
            for (int t = 0; t < NT; ++t) {
                half8 bf = *(const half8*)(Bk + t * 16 * 32);
                acc[0][t] = __builtin_amdgcn_mfma_f32_16x16x32_f16(af0, bf, acc[0][t], 0, 0, 0);
                acc[1][t] = __builtin_amdgcn_mfma_f32_16x16x32_f16(af1, bf, acc[1][t], 0, 0, 0);
            }
        }
    }
#pragma unroll
    for (int r = 0; r < 2; ++r) {
        int rowb = row0 + r * 16 + quad * 4;
#pragma unroll
        for (int t = 0; t < NT; ++t) {
            int col = t * 16 + nq;
            if (col >= HD) continue;
            float bj = bias[col];
#pragma unroll
            for (int g = 0; g < 4; ++g) {
                int row = rowb + g;
                if (row < n)
                    out16[(size_t)row * KPAD + col] = (h16)fmaxf(acc[r][t][g] + bj, 0.0f);
            }
        }
    }
}

// ---------- fused segmented pool (mean+max) + FC + log_softmax (fp16 input) ----------
__global__ __launch_bounds__(256) void k_pool_fc(
    const h16* __restrict__ Hf, const int* __restrict__ gstart,
    const float* __restrict__ fcw, const float* __restrict__ fcb,
    float* __restrict__ out) {
    __shared__ float red[8];
    int g = blockIdx.x;
    int j = threadIdx.x;
    int i0 = gstart[g], i1 = gstart[g + 1];
    float s0 = 0.f, s1 = 0.f, s2 = 0.f, s3 = 0.f, mx = 0.f;   // post-ReLU: max >= 0
    if (j < HD) {
        int i = i0;
        for (; i + 3 < i1; i += 4) {
            float v0 = (float)Hf[(size_t)i * KPAD + j];
            float v1 = (float)Hf[(size_t)(i + 1) * KPAD + j];
            float v2 = (float)Hf[(size_t)(i + 2) * KPAD + j];
            float v3 = (float)Hf[(size_t)(i + 3) * KPAD + j];
            s0 += v0; s1 += v1; s2 += v2; s3 += v3;
            mx = fmaxf(mx, fmaxf(fmaxf(v0, v1), fmaxf(v2, v3)));
        }
        for (; i < i1; ++i) {
            float v = (float)Hf[(size_t)i * KPAD + j];
            s0 += v; mx = fmaxf(mx, v);
        }
    }
    float cntf = (float)(i1 - i0);
    float mean = (s0 + s1 + s2 + s3) / fmaxf(cntf, 1.f);
    float p0 = 0.f, p1 = 0.f;
    if (j < HD) {
        p0 = mean * fcw[2 * j]     + mx * fcw[2 * (HD + j)];
        p1 = mean * fcw[2 * j + 1] + mx * fcw[2 * (HD + j) + 1];
    }
#pragma unroll
    for (int o = 32; o > 0; o >>= 1) {
        p0 += __shfl_down(p0, o);
        p1 += __shfl_down(p1, o);
    }
    int wave = j >> 6, lane = j & 63;
    if (lane == 0) { red[wave * 2] = p0; red[wave * 2 + 1] = p1; }
    __syncthreads();
    if (j == 0) {
        float z0 = red[0] + red[2] + red[4] + red[6] + fcb[0];
        float z1 = red[1] + red[3] + red[5] + red[7] + fcb[1];
        float m = fmaxf(z0, z1);
        float lse = m + logf(expf(z0 - m) + expf(z1 - m));
        out[g * 2 + 0] = z0 - lse;
        out[g * 2 + 1] = z1 - lse;
    }
}

extern "C" void kernel_launch(void* const* d_in, const int* in_sizes, int n_in,
                              void* d_out, int out_size, void* d_ws, size_t ws_size,
                              hipStream_t stream) {
    const float* x     = (const float*)d_in[0];
    const int*   edge  = (const int*)d_in[1];
    const int*   batch = (const int*)d_in[2];
    const float* lmax  = (const float*)d_in[3];
    const float* W1 = (const float*)d_in[4];  const float* b1 = (const float*)d_in[5];
    const float* W2 = (const float*)d_in[6];  const float* b2 = (const float*)d_in[7];
    const float* W3 = (const float*)d_in[8];  const float* b3 = (const float*)d_in[9];
    const float* W4 = (const float*)d_in[10]; const float* b4 = (const float*)d_in[11];
    const float* fcw = (const float*)d_in[12]; const float* fcb = (const float*)d_in[13];
    float* out = (float*)d_out;

    const int n = NN, E = NE;
    const int* src = edge;
    const int* dst = edge + E;

    // workspace layout (float units, each buffer 16B-aligned)
    float* ws = (float*)d_ws;
    size_t off = 0;
    auto alloc = [&](size_t nfloats) { float* p = ws + off; off += (nfloats + 3) & ~(size_t)3; return p; };
    int*   degi   = (int*)alloc(NN);
    float* dis    = alloc(NN);
    float* qs     = alloc(NN);
    float* diag   = alloc(NN);
    int*   cntd   = (int*)alloc(NN);
    int*   rowst  = (int*)alloc(NN);
    int*   bsum   = (int*)alloc(SCAN_B);
    u64*   csr    = (u64*)alloc((size_t)NE * 2);            // packed {src, w}
    int*   gstart = (int*)alloc(NG + 1);
    unsigned* pSrc = (unsigned*)alloc((size_t)2 * 256 * HB);  // src histogram partials
    unsigned* pDst = (unsigned*)alloc((size_t)2 * 256 * HB);  // dst histogram partials/bases
    h16*   x16    = (h16*)alloc((size_t)MP * FIN / 2);      // fp16 x (stride 64)
    h16*   hi0    = (h16*)alloc((size_t)MP * KPAD / 2);     // fp16 h (inter-layer, in-place)
    h16*   hi1    = (h16*)alloc((size_t)MP * KPAD / 2);     // fp16 Tx1 / final features
    h16*   hi2    = (h16*)alloc((size_t)MP * KPAD / 2);     // fp16 Tx2
    const int WSZ0 = 3 * 2 * 208 * 32;
    const int WSZ  = 3 * 7 * 208 * 32;
    h16* wt0 = (h16*)alloc(WSZ0 / 2);
    h16* wt1 = (h16*)alloc(WSZ / 2);
    h16* wt2 = (h16*)alloc(WSZ / 2);
    h16* wt3 = (h16*)alloc(WSZ / 2);

    dim3 blk(256);
    int gN = (n + 255) / 256;
    int gScan = (n + SCAN_B - 1) / SCAN_B;
    int gGemm = MP / 128;                       // 391 blocks, 4 waves x 32 rows
    int gWp = (WSZ0 + 3 * WSZ + NN * FIN + 255) / 256;

    // --- setup (no memsets: every consumed byte is written this call; A k-pad /
    //     tail-row garbage is nullified by zeroed B k-pads + row<n store guard) ---
    k_wprep<<<gWp, blk, 0, stream>>>(W1, W2, W3, W4, wt0, wt1, wt2, wt3, x, x16);
    k_hist<<<512, blk, 0, stream>>>(src, dst, pSrc, pDst, E);
    k_hredscan<<<(4 * HB + 255) / 256, blk, 0, stream>>>(pSrc, pDst, degi, cntd, n);
    k_prep<<<gN + 2, blk, 0, stream>>>(degi, batch, lmax, dis, qs, diag, gstart, n, gN);
    k_scan1<<<gScan, blk, 0, stream>>>(cntd, rowst, bsum, n);
    k_scan2<<<1, blk, 0, stream>>>(bsum, gScan);
    k_scan3<<<gScan, blk, 0, stream>>>(rowst, bsum, n);
    k_fillcsr2<<<256, blk, 0, stream>>>(src, dst, qs, dis, rowst, pDst, csr, E);

    // --- 4 Chebyshev layers (standalone oversubscribed gathers + MFMA gemm) ---
    const h16* wt[4] = {wt0, wt1, wt2, wt3};
    const float* bl[4] = {b1, b2, b3, b4};
    for (int l = 0; l < 4; l++) {
        int s16 = (l == 0) ? FIN : KPAD;
        int lsh = (l == 0) ? 4 : 6;                  // 16-lane groups (l0) / full wave
        int per = 256 >> lsh;
        int gGat = (n + per - 1) / per;
        int ksteps = (l == 0) ? 2 : 7;
        const h16* a0 = (l == 0) ? x16 : hi0;
        // Tx1 = prop(Tx0) -> hi1
        k_gather<<<gGat, blk, 0, stream>>>(rowst, cntd, csr, diag, a0, a0, hi1, s16, lsh, n, 0);
        // Tx2 = 2*prop(Tx1) - Tx0 -> hi2
        k_gather<<<gGat, blk, 0, stream>>>(rowst, cntd, csr, diag, hi1, a0, hi2, s16, lsh, n, 1);
        // out = relu([Tx0|Tx1|Tx2] @ W + b) -> hi0 (layers 0-2) or hi1 (final, pool input)
        k_gemm16<<<gGemm, blk, 0, stream>>>(a0, hi1, hi2, s16, ksteps, wt[l], bl[l],
                                            (l < 3) ? hi0 : hi1, n);
    }

    // --- fused pool + FC head (no atomics; batch is sorted; fp16 input) ---
    k_pool_fc<<<NG, blk, 0, stream>>>(hi1, gstart, fcw, fcb, out);
}

// Round 14
// 780.170 us; speedup vs baseline: 1.3119x; 1.0281x over previous
//
#include <hip/hip_runtime.h>
#include <math.h>

#define NN 50000
#define MP 50048          // NN padded to multiple of 128 (32 rows x 4 waves)
#define NE 800000
#define FIN 64
#define HD 200
#define NG 256
#define SCAN_B 256
#define KPAD 224          // HD padded to multiple of 32 for MFMA K-steps
#define NT 13             // 13 * 16 = 208 >= 200 output col tiles
#define HB 12544          // LDS histogram packed dwords (covers 25088 nodes/pass)
#define PER_B 3125        // NE / 256 edges per histogram block

typedef _Float16 h16;
typedef __attribute__((ext_vector_type(8))) _Float16 half8;
typedef __attribute__((ext_vector_type(4))) float float4v;
typedef unsigned long long u64;

// ---------- dual histogram: blocks 0-255 src -> pSrc, 256-511 dst -> pDst ----------
__global__ __launch_bounds__(256) void k_hist(const int* __restrict__ src,
                                              const int* __restrict__ dst,
                                              unsigned* __restrict__ pSrc,
                                              unsigned* __restrict__ pDst, int E) {
    __shared__ unsigned h[HB];
    int tid = threadIdx.x;
    int isDst = blockIdx.x >> 8;
    int b = blockIdx.x & 255;
    const int* idx = isDst ? dst : src;
    unsigned* partial = isDst ? pDst : pSrc;
    int e0 = b * PER_B;
    int v[13];
#pragma unroll
    for (int j = 0; j < 13; ++j) {
        int o = j * 256 + tid;
        v[j] = (o < PER_B) ? idx[e0 + o] : -1;
    }
#pragma unroll
    for (int pass = 0; pass < 2; ++pass) {
        for (int t = tid; t < HB; t += 256) h[t] = 0;
        __syncthreads();
        int lo = pass * (2 * HB);
#pragma unroll
        for (int j = 0; j < 13; ++j) {
            int vv = v[j] - lo;
            if (vv >= 0 && vv < 2 * HB)
                atomicAdd(&h[vv >> 1], (vv & 1) ? 0x10000u : 1u);
        }
        __syncthreads();
        unsigned* pb = partial + ((size_t)pass * 256 + b) * HB;
        for (int t = tid; t < HB; t += 256) pb[t] = h[t];
        __syncthreads();
    }
}

// ---------- fused: reduce src partials -> degi ; scan dst partials -> bases + cntd ----------
__global__ void k_hredscan(const unsigned* __restrict__ pSrc, unsigned* __restrict__ pDst,
                           int* __restrict__ degi, int* __restrict__ cntd, int n) {
    int i = blockIdx.x * blockDim.x + threadIdx.x;
    if (i < 2 * HB) {
        int pass = i / HB, p = i - pass * HB;
        const unsigned* pb = pSrc + (size_t)pass * 256 * HB + p;
        unsigned s = 0;
        for (int b = 0; b < 256; ++b) s += pb[(size_t)b * HB];
        int n0 = pass * 2 * HB + 2 * p;
        if (n0 < n)     degi[n0]     = (int)(s & 0xffffu);
        if (n0 + 1 < n) degi[n0 + 1] = (int)(s >> 16);
    } else if (i < 4 * HB) {
        int j = i - 2 * HB;
        int pass = j / HB, p = j - pass * HB;
        unsigned* pb = pDst + (size_t)pass * 256 * HB + p;
        unsigned run = 0;
        for (int b = 0; b < 256; ++b) {
            unsigned c = pb[(size_t)b * HB];
            pb[(size_t)b * HB] = run;
            run += c;
        }
        int n0 = pass * 2 * HB + 2 * p;
        if (n0 < n)     cntd[n0]     = (int)(run & 0xffffu);
        if (n0 + 1 < n) cntd[n0 + 1] = (int)(run >> 16);
    }
}

// ---------- fused node prep (dis/qs/diag) + graph bounds ----------
__global__ void k_prep(const int* __restrict__ degi, const int* __restrict__ batch,
                       const float* __restrict__ lmax, float* __restrict__ dis,
                       float* __restrict__ qs, float* __restrict__ diag,
                       int* __restrict__ gstart, int n, int gN) {
    int b = blockIdx.x;
    if (b < gN) {
        int i = b * 256 + threadIdx.x;
        if (i < n) {
            int d = degi[i];
            float di = (d > 0) ? (1.0f / sqrtf((float)d)) : 0.0f;
            float sc = 2.0f / lmax[batch[i]];
            dis[i] = di;
            qs[i] = -di * sc;
            diag[i] = sc - 1.0f;
        }
    } else {
        int g = (b - gN) * 256 + threadIdx.x;
        if (g > NG) return;
        if (g == NG) { gstart[NG] = n; return; }
        int lo = 0, hi = n;
        while (lo < hi) {
            int mid = (lo + hi) >> 1;
            if (batch[mid] < g) lo = mid + 1; else hi = mid;
        }
        gstart[g] = lo;
    }
}

// ---------- exclusive scan over cnt_dst (block-local; global base added by consumers) ----------
__global__ void k_scan1(const int* __restrict__ cnt, int* __restrict__ excl,
                        int* __restrict__ bsum, int n) {
    __shared__ int sh[SCAN_B];
    int tid = threadIdx.x;
    int i = blockIdx.x * SCAN_B + tid;
    int v = (i < n) ? cnt[i] : 0;
    sh[tid] = v;
    __syncthreads();
    for (int off = 1; off < SCAN_B; off <<= 1) {
        int t = (tid >= off) ? sh[tid - off] : 0;
        __syncthreads();
        sh[tid] += t;
        __syncthreads();
    }
    if (i < n) excl[i] = sh[tid] - v;
    if (tid == SCAN_B - 1) bsum[blockIdx.x] = sh[tid];
}

__global__ void k_scan2(int* __restrict__ bsum, int nb) {
    __shared__ int sh[SCAN_B];
    int tid = threadIdx.x;
    int v = (tid < nb) ? bsum[tid] : 0;
    sh[tid] = v;
    __syncthreads();
    for (int off = 1; off < SCAN_B; off <<= 1) {
        int t = (tid >= off) ? sh[tid - off] : 0;
        __syncthreads();
        sh[tid] += t;
        __syncthreads();
    }
    if (tid < nb) bsum[tid] = sh[tid] - v;   // exclusive over block totals
}

// ---------- CSR fill, zero global atomics (bases from scanned dst partials) ----------
// rowstart[d] computed inline as excl[d] + bsum[d>>8] (bsum table is L1-hot).
__global__ __launch_bounds__(256) void k_fillcsr2(
    const int* __restrict__ src, const int* __restrict__ dst,
    const float* __restrict__ qs, const float* __restrict__ dis,
    const int* __restrict__ excl, const int* __restrict__ bsum,
    const unsigned* __restrict__ hpart, u64* __restrict__ csr, int E) {
    __shared__ unsigned lrank[HB];
    int tid = threadIdx.x;
    int e0 = blockIdx.x * PER_B;
    int vs[13], vd[13];
#pragma unroll
    for (int j = 0; j < 13; ++j) {
        int o = j * 256 + tid;
        vs[j] = (o < PER_B) ? src[e0 + o] : -1;
        vd[j] = (o < PER_B) ? dst[e0 + o] : -1;
    }
#pragma unroll
    for (int pass = 0; pass < 2; ++pass) {
        for (int t = tid; t < HB; t += 256) lrank[t] = 0;
        __syncthreads();
        int lo = pass * (2 * HB);
        const unsigned* base = hpart + ((size_t)pass * 256 + blockIdx.x) * HB;
#pragma unroll
        for (int j = 0; j < 13; ++j) {
            int vv = vd[j] - lo;
            if (vv >= 0 && vv < 2 * HB) {
                unsigned old = atomicAdd(&lrank[vv >> 1], (vv & 1) ? 0x10000u : 1u);
                unsigned rank = (vv & 1) ? (old >> 16) : (old & 0xffffu);
                unsigned bs = base[vv >> 1];
                unsigned bb = (vv & 1) ? (bs >> 16) : (bs & 0xffffu);
                int s = vs[j], d = vd[j];
                int pos = excl[d] + bsum[d >> 8] + (int)bb + (int)rank;
                float w = qs[s] * dis[d];
                csr[pos] = (unsigned)s | ((u64)__float_as_uint(w) << 32);
            }
        }
        __syncthreads();
    }
}

// ---------- W pre-transpose (all 4 layers) + x fp32->fp16, one launch ----------
// fp16 [seg][ks][208][32]; B k-pads are ZERO -> A k-pads never need zeroing.
__global__ void k_wprep(const float* __restrict__ W1, const float* __restrict__ W2,
                        const float* __restrict__ W3, const float* __restrict__ W4,
                        h16* __restrict__ wt0, h16* __restrict__ wt1,
                        h16* __restrict__ wt2, h16* __restrict__ wt3,
                        const float* __restrict__ x, h16* __restrict__ x16) {
    const int T0 = 3 * 2 * 208 * 32, T = 3 * 7 * 208 * 32;
    const int TW = T0 + 3 * T;
    int idx = blockIdx.x * blockDim.x + threadIdx.x;
    if (idx >= TW) {                      // tail: x split (NN*FIN elements)
        int i = idx - TW;
        if (i < NN * FIN) x16[i] = (h16)x[i];
        return;
    }
    const float* W; h16* o; int fin, ksteps, li;
    if (idx < T0) { W = W1; o = wt0; fin = FIN; ksteps = 2; li = idx; }
    else {
        int r = idx - T0; int l = r / T;
        li = r - l * T; fin = HD; ksteps = 7;
        W = (l == 0) ? W2 : ((l == 1) ? W3 : W4);
        o = (l == 0) ? wt1 : ((l == 1) ? wt2 : wt3);
    }
    int kk = li & 31;
    int r2 = li >> 5;
    int nn = r2 % 208;
    int r3 = r2 / 208;
    int ks = r3 % ksteps;
    int seg = r3 / ksteps;
    int k = ks * 32 + kk;
    o[li] = (nn < HD && k < fin) ? (h16)W[((size_t)seg * fin + k) * HD + nn] : (h16)0.f;
}

// ---------- propagation (gather, fp16, 8-deep load pipeline — R11-best config) ----------
// One lane-group per node: group = 2^lsh lanes (64 for s16=224, 16 for s16=64).
// Oversubscribed wave-per-node grid = the MLP that makes this fast (R12 lesson).
// 12-deep regressed (R13: occupancy 60->43%, 66->70 us) — 8 is the sweet spot.
// mode 0: v = gath + diag*hin        mode 1: v = 2*(gath + diag*hin) - hin0
__global__ __launch_bounds__(256) void k_gather(
    const int* __restrict__ excl, const int* __restrict__ bsum,
    const int* __restrict__ rowcnt,
    const u64* __restrict__ csr, const float* __restrict__ diag,
    const h16* __restrict__ hin16, const h16* __restrict__ h016,
    h16* __restrict__ hout16, int s16, int lsh, int n, int mode) {
    int per = 256 >> lsh;
    int i = blockIdx.x * per + (threadIdx.x >> lsh);
    if (i >= n) return;
    int lane = threadIdx.x & ((1 << lsh) - 1);
    int c0 = lane * 4;
    if (c0 >= s16) return;
    int start = excl[i] + bsum[i >> 8];
    int cnt = rowcnt[i];
    float g0 = 0.f, g1 = 0.f, g2 = 0.f, g3 = 0.f;
    union U { uint2 u; h16 h[4]; };
    const u64* cp = csr + start;
    int k = 0;
    for (; k + 7 < cnt; k += 8) {
        u64 e[8];
#pragma unroll
        for (int j = 0; j < 8; ++j) e[j] = cp[k + j];           // broadcast, independent
        U p[8];
#pragma unroll
        for (int j = 0; j < 8; ++j)                              // 8 rows in flight
            p[j].u = *(const uint2*)(hin16 + (size_t)(unsigned)(e[j] & 0xffffffffu) * s16 + c0);
#pragma unroll
        for (int j = 0; j < 8; ++j) {
            float w = __uint_as_float((unsigned)(e[j] >> 32));
            g0 += w * (float)p[j].h[0];
            g1 += w * (float)p[j].h[1];
            g2 += w * (float)p[j].h[2];
            g3 += w * (float)p[j].h[3];
        }
    }
    for (; k + 1 < cnt; k += 2) {
        u64 e0 = cp[k], e1 = cp[k + 1];
        U p0, p1;
        p0.u = *(const uint2*)(hin16 + (size_t)(unsigned)(e0 & 0xffffffffu) * s16 + c0);
        p1.u = *(const uint2*)(hin16 + (size_t)(unsigned)(e1 & 0xffffffffu) * s16 + c0);
        float w0 = __uint_as_float((unsigned)(e0 >> 32));
        float w1 = __uint_as_float((unsigned)(e1 >> 32));
        g0 += w0 * (float)p0.h[0] + w1 * (float)p1.h[0];
        g1 += w0 * (float)p0.h[1] + w1 * (float)p1.h[1];
        g2 += w0 * (float)p0.h[2] + w1 * (float)p1.h[2];
        g3 += w0 * (float)p0.h[3] + w1 * (float)p1.h[3];
    }
    if (k < cnt) {
        u64 e0 = cp[k];
        U p0;
        p0.u = *(const uint2*)(hin16 + (size_t)(unsigned)(e0 & 0xffffffffu) * s16 + c0);
        float w0 = __uint_as_float((unsigned)(e0 >> 32));
        g0 += w0 * (float)p0.h[0];
        g1 += w0 * (float)p0.h[1];
        g2 += w0 * (float)p0.h[2];
        g3 += w0 * (float)p0.h[3];
    }
    float dg = diag[i];
    U hs; hs.u = *(const uint2*)(hin16 + (size_t)i * s16 + c0);
    float v0 = g0 + dg * (float)hs.h[0];
    float v1 = g1 + dg * (float)hs.h[1];
    float v2 = g2 + dg * (float)hs.h[2];
    float v3 = g3 + dg * (float)hs.h[3];
    if (mode == 1) {
        U h0; h0.u = *(const uint2*)(h016 + (size_t)i * s16 + c0);
        v0 = 2.f * v0 - (float)h0.h[0];
        v1 = 2.f * v1 - (float)h0.h[1];
        v2 = 2.f * v2 - (float)h0.h[2];
        v3 = 2.f * v3 - (float)h0.h[3];
    }
    U o;
    o.h[0] = (h16)v0; o.h[1] = (h16)v1; o.h[2] = (h16)v2; o.h[3] = (h16)v3;
    *(uint2*)(hout16 + (size_t)i * s16 + c0) = o.u;
}

// ---------- MFMA fp16 GEMM, barrier-free: out = relu([A0|A1|A2] @ W + b) ----------
// Each wave: 32 rows x 208 cols. In-place out16 over an A-buffer is safe:
// each row is read only by the wave that writes it, reads precede epilogue.
__global__ __launch_bounds__(256) void k_gemm16(
    const h16* __restrict__ A0, const h16* __restrict__ A1, const h16* __restrict__ A2,
    int strideA, int ksteps,
    const h16* __restrict__ Wt, const float* __restrict__ bias,
    h16* __restrict__ out16, int n) {
    int tid = threadIdx.x;
    int wave = tid >> 6, lane = tid & 63;
    int nq = lane & 15, quad = lane >> 4;
    int row0 = (blockIdx.x * 4 + wave) * 32;
    const h16* Aseg[3] = {A0, A1, A2};

    float4v acc[2][NT];
#pragma unroll
    for (int r = 0; r < 2; r++)
#pragma unroll
        for (int t = 0; t < NT; t++) acc[r][t] = (float4v)0.f;

    for (int seg = 0; seg < 3; ++seg) {
        const h16* Ab = Aseg[seg] + (size_t)(row0 + nq) * strideA + quad * 8;
        const h16* Bb = Wt + (size_t)seg * ksteps * 208 * 32 + (size_t)nq * 32 + quad * 8;
        for (int ks = 0; ks < ksteps; ++ks) {
            half8 af0 = *(const half8*)(Ab + ks * 32);
            half8 af1 = *(const half8*)(Ab + 16 * strideA + ks * 32);
            const h16* Bk = Bb + (size_t)ks * 208 * 32;
#pragma unroll
            for (int t = 0; t < NT; ++t) {
                half8 bf = *(const half8*)(Bk + t * 16 * 32);
                acc[0][t] = __builtin_amdgcn_mfma_f32_16x16x32_f16(af0, bf, acc[0][t], 0, 0, 0);
                acc[1][t] = __builtin_amdgcn_mfma_f32_16x16x32_f16(af1, bf, acc[1][t], 0, 0, 0);
            }
        }
    }
#pragma unroll
    for (int r = 0; r < 2; ++r) {
        int rowb = row0 + r * 16 + quad * 4;
#pragma unroll
        for (int t = 0; t < NT; ++t) {
            int col = t * 16 + nq;
            if (col >= HD) continue;
            float bj = bias[col];
#pragma unroll
            for (int g = 0; g < 4; ++g) {
                int row = rowb + g;
                if (row < n)
                    out16[(size_t)row * KPAD + col] = (h16)fmaxf(acc[r][t][g] + bj, 0.0f);
            }
        }
    }
}

// ---------- fused segmented pool (mean+max) + FC + log_softmax (fp16 input) ----------
__global__ __launch_bounds__(256) void k_pool_fc(
    const h16* __restrict__ Hf, const int* __restrict__ gstart,
    const float* __restrict__ fcw, const float* __restrict__ fcb,
    float* __restrict__ out) {
    __shared__ float red[8];
    int g = blockIdx.x;
    int j = threadIdx.x;
    int i0 = gstart[g], i1 = gstart[g + 1];
    float s0 = 0.f, s1 = 0.f, s2 = 0.f, s3 = 0.f, mx = 0.f;   // post-ReLU: max >= 0
    if (j < HD) {
        int i = i0;
        for (; i + 3 < i1; i += 4) {
            float v0 = (float)Hf[(size_t)i * KPAD + j];
            float v1 = (float)Hf[(size_t)(i + 1) * KPAD + j];
            float v2 = (float)Hf[(size_t)(i + 2) * KPAD + j];
            float v3 = (float)Hf[(size_t)(i + 3) * KPAD + j];
            s0 += v0; s1 += v1; s2 += v2; s3 += v3;
            mx = fmaxf(mx, fmaxf(fmaxf(v0, v1), fmaxf(v2, v3)));
        }
        for (; i < i1; ++i) {
            float v = (float)Hf[(size_t)i * KPAD + j];
            s0 += v; mx = fmaxf(mx, v);
        }
    }
    float cntf = (float)(i1 - i0);
    float mean = (s0 + s1 + s2 + s3) / fmaxf(cntf, 1.f);
    float p0 = 0.f, p1 = 0.f;
    if (j < HD) {
        p0 = mean * fcw[2 * j]     + mx * fcw[2 * (HD + j)];
        p1 = mean * fcw[2 * j + 1] + mx * fcw[2 * (HD + j) + 1];
    }
#pragma unroll
    for (int o = 32; o > 0; o >>= 1) {
        p0 += __shfl_down(p0, o);
        p1 += __shfl_down(p1, o);
    }
    int wave = j >> 6, lane = j & 63;
    if (lane == 0) { red[wave * 2] = p0; red[wave * 2 + 1] = p1; }
    __syncthreads();
    if (j == 0) {
        float z0 = red[0] + red[2] + red[4] + red[6] + fcb[0];
        float z1 = red[1] + red[3] + red[5] + red[7] + fcb[1];
        float m = fmaxf(z0, z1);
        float lse = m + logf(expf(z0 - m) + expf(z1 - m));
        out[g * 2 + 0] = z0 - lse;
        out[g * 2 + 1] = z1 - lse;
    }
}

extern "C" void kernel_launch(void* const* d_in, const int* in_sizes, int n_in,
                              void* d_out, int out_size, void* d_ws, size_t ws_size,
                              hipStream_t stream) {
    const float* x     = (const float*)d_in[0];
    const int*   edge  = (const int*)d_in[1];
    const int*   batch = (const int*)d_in[2];
    const float* lmax  = (const float*)d_in[3];
    const float* W1 = (const float*)d_in[4];  const float* b1 = (const float*)d_in[5];
    const float* W2 = (const float*)d_in[6];  const float* b2 = (const float*)d_in[7];
    const float* W3 = (const float*)d_in[8];  const float* b3 = (const float*)d_in[9];
    const float* W4 = (const float*)d_in[10]; const float* b4 = (const float*)d_in[11];
    const float* fcw = (const float*)d_in[12]; const float* fcb = (const float*)d_in[13];
    float* out = (float*)d_out;

    const int n = NN, E = NE;
    const int* src = edge;
    const int* dst = edge + E;

    // workspace layout (float units, each buffer 16B-aligned)
    float* ws = (float*)d_ws;
    size_t off = 0;
    auto alloc = [&](size_t nfloats) { float* p = ws + off; off += (nfloats + 3) & ~(size_t)3; return p; };
    int*   degi   = (int*)alloc(NN);
    float* dis    = alloc(NN);
    float* qs     = alloc(NN);
    float* diag   = alloc(NN);
    int*   cntd   = (int*)alloc(NN);
    int*   excl   = (int*)alloc(NN);
    int*   bsum   = (int*)alloc(SCAN_B);
    u64*   csr    = (u64*)alloc((size_t)NE * 2);            // packed {src, w}
    int*   gstart = (int*)alloc(NG + 1);
    unsigned* pSrc = (unsigned*)alloc((size_t)2 * 256 * HB);  // src histogram partials
    unsigned* pDst = (unsigned*)alloc((size_t)2 * 256 * HB);  // dst histogram partials/bases
    h16*   x16    = (h16*)alloc((size_t)MP * FIN / 2);      // fp16 x (stride 64)
    h16*   hi0    = (h16*)alloc((size_t)MP * KPAD / 2);     // fp16 h (inter-layer, in-place)
    h16*   hi1    = (h16*)alloc((size_t)MP * KPAD / 2);     // fp16 Tx1 / final features
    h16*   hi2    = (h16*)alloc((size_t)MP * KPAD / 2);     // fp16 Tx2
    const int WSZ0 = 3 * 2 * 208 * 32;
    const int WSZ  = 3 * 7 * 208 * 32;
    h16* wt0 = (h16*)alloc(WSZ0 / 2);
    h16* wt1 = (h16*)alloc(WSZ / 2);
    h16* wt2 = (h16*)alloc(WSZ / 2);
    h16* wt3 = (h16*)alloc(WSZ / 2);

    dim3 blk(256);
    int gN = (n + 255) / 256;
    int gScan = (n + SCAN_B - 1) / SCAN_B;      // 196
    int gGemm = MP / 128;                       // 391 blocks, 4 waves x 32 rows
    int gWp = (WSZ0 + 3 * WSZ + NN * FIN + 255) / 256;

    // --- setup (no memsets: every consumed byte is written this call; A k-pad /
    //     tail-row garbage is nullified by zeroed B k-pads + row<n store guard) ---
    k_wprep<<<gWp, blk, 0, stream>>>(W1, W2, W3, W4, wt0, wt1, wt2, wt3, x, x16);
    k_hist<<<512, blk, 0, stream>>>(src, dst, pSrc, pDst, E);
    k_hredscan<<<(4 * HB + 255) / 256, blk, 0, stream>>>(pSrc, pDst, degi, cntd, n);
    k_prep<<<gN + 2, blk, 0, stream>>>(degi, batch, lmax, dis, qs, diag, gstart, n, gN);
    k_scan1<<<gScan, blk, 0, stream>>>(cntd, excl, bsum, n);
    k_scan2<<<1, blk, 0, stream>>>(bsum, gScan);
    k_fillcsr2<<<256, blk, 0, stream>>>(src, dst, qs, dis, excl, bsum, pDst, csr, E);

    // --- 4 Chebyshev layers (standalone oversubscribed gathers + MFMA gemm) ---
    const h16* wt[4] = {wt0, wt1, wt2, wt3};
    const float* bl[4] = {b1, b2, b3, b4};
    for (int l = 0; l < 4; l++) {
        int s16 = (l == 0) ? FIN : KPAD;
        int lsh = (l == 0) ? 4 : 6;                  // 16-lane groups (l0) / full wave
        int per = 256 >> lsh;
        int gGat = (n + per - 1) / per;
        int ksteps = (l == 0) ? 2 : 7;
        const h16* a0 = (l == 0) ? x16 : hi0;
        // Tx1 = prop(Tx0) -> hi1
        k_gather<<<gGat, blk, 0, stream>>>(excl, bsum, cntd, csr, diag, a0, a0, hi1, s16, lsh, n, 0);
        // Tx2 = 2*prop(Tx1) - Tx0 -> hi2
        k_gather<<<gGat, blk, 0, stream>>>(excl, bsum, cntd, csr, diag, hi1, a0, hi2, s16, lsh, n, 1);
        // out = relu([Tx0|Tx1|Tx2] @ W + b) -> hi0 (layers 0-2) or hi1 (final, pool input)
        k_gemm16<<<gGemm, blk, 0, stream>>>(a0, hi1, hi2, s16, ksteps, wt[l], bl[l],
                                            (l < 3) ? hi0 : hi1, n);
    }

    // --- fused pool + FC head (no atomics; batch is sorted; fp16 input) ---
    k_pool_fc<<<NG, blk, 0, stream>>>(hi1, gstart, fcw, fcb, out);
}